// Round 7
// baseline (738.430 us; speedup 1.0000x reference)
//
#include <hip/hip_runtime.h>

typedef short bf16x8 __attribute__((ext_vector_type(8)));
typedef float f32x16 __attribute__((ext_vector_type(16)));

constexpr int S = 2048;
constexpr int H = 16;
constexpr int D = 128;
constexpr int BM = 128;    // q rows per phase (4 q-groups x 32)
constexpr int TILE = 8192; // shorts per 64-row K/V tile (16 KB)
constexpr int KSTR = 136;  // prepass staging LDS stride (shorts)
constexpr int MST  = 33;   // merge scratch stride (floats)

// ---------------------------------------------------------------------------
// Workspace layouts (per (b,h), 32 tiles of 16KB), both REGISTER-direct:
//  K tile (chunk-major): [chunk 0..15][row 0..63] x 16B.  Fragment c of wave
//     (qw,nt): lane(ln,half) reads chunk 2c+half, row nt*32+ln -> coalesced
//     global_load_dwordx4 (consecutive lanes = consecutive 16B).
//  V tile (cc-major, sigma column order): [cc 0..7][d 0..127] x 16B; chunk cc
//     holds k-pairs in the order matching pk2-packed P (sigma interleave).
//
// fa_fwd v7 (16-wave): 256 blocks x 1024 thr, 1 block/CU, q-pair schedule
// (exactly 34 tiles/block; phase tile counts are always EVEN).  Wave (qw,nt,jt)
// handles q-group qw, k-half nt, and tiles jj = 2i+jt -> 4 waves/SIMD at
// constant per-CU work (R6's 2 waves/SIMD left MFMA 18% / VALU 28% with issue
// gaps from exp2->pk2->MFMA chains).  NO barriers in the j-loop; waves sync
// only at the per-phase 4-partial merge (3 writers -> LDS, pi=0 adds+stores).
// ---------------------------------------------------------------------------

__device__ inline unsigned int pk2(float a, float b) {
    // pack 2 f32 -> 2 bf16 (RNE bit-trick; finite values only). low=a, high=b
    unsigned int ua = __builtin_bit_cast(unsigned int, a);
    unsigned int ub = __builtin_bit_cast(unsigned int, b);
    ua += 0x7fffu + ((ua >> 16) & 1u);
    ub += 0x7fffu + ((ub >> 16) & 1u);
    return (ua >> 16) | (ub & 0xffff0000u);
}

// ---- fused prepass: K -> chunk-major bf16 tiles; V -> transposed cc-major ----
__global__ __launch_bounds__(256) void cvt_kv(const float* __restrict__ K,
                                              const float* __restrict__ V,
                                              unsigned short* __restrict__ Kb,
                                              unsigned short* __restrict__ Vtb) {
    __shared__ unsigned short Kst[64 * KSTR];
    __shared__ unsigned short Vst[64 * KSTR];
    __shared__ unsigned short Vout[TILE];
    const int tid = threadIdx.x;
    const int t   = blockIdx.x;   // 64-row tile
    const int bh  = blockIdx.y;
    const int b = bh >> 4, h = bh & 15;
    const size_t base = ((size_t)(b * S + t * 64) * H + h) * D;

    // --- stage K and V rows into LDS (coalesced reads, cvt to bf16) ---
    #pragma unroll
    for (int u = 0; u < 4; ++u) {
        const int c   = tid + 256 * u;
        const int n   = c >> 4;
        const int off = (c & 15) * 8;
        const float* pk = K + base + (size_t)n * (H * D) + off;
        float4 f0 = *(const float4*)pk;
        float4 f1 = *(const float4*)(pk + 4);
        unsigned int w[4];
        w[0] = pk2(f0.x, f0.y); w[1] = pk2(f0.z, f0.w);
        w[2] = pk2(f1.x, f1.y); w[3] = pk2(f1.z, f1.w);
        *(uint4*)&Kst[n * KSTR + off] = *(const uint4*)w;
        const float* pv = V + base + (size_t)n * (H * D) + off;
        f0 = *(const float4*)pv;
        f1 = *(const float4*)(pv + 4);
        w[0] = pk2(f0.x, f0.y); w[1] = pk2(f0.z, f0.w);
        w[2] = pk2(f1.x, f1.y); w[3] = pk2(f1.z, f1.w);
        *(uint4*)&Vst[n * KSTR + off] = *(const uint4*)w;
    }
    __syncthreads();

    // --- K: chunk-major linear write ---
    unsigned short* outK = Kb + ((size_t)bh * 32 + t) * TILE;
    #pragma unroll
    for (int u = 0; u < 4; ++u) {
        const int s = u * 256 + tid;        // 16B slot = chunk*64 + row
        const int chunk = s >> 6;
        const int row   = s & 63;
        *(uint4*)(outK + s * 8) = *(const uint4*)&Kst[row * KSTR + chunk * 8];
    }

    // --- V: transpose (sigma pair-interleave) into cc-major Vout, write linear ---
    const int d  = tid >> 1;
    const int kh = (tid & 1) * 32;
    unsigned short tmp[32];
    #pragma unroll
    for (int m = 0; m < 32; ++m) {
        const int sig = kh + m;
        const int k = (sig & ~12) | ((sig & 4) << 1) | ((sig & 8) >> 1);
        tmp[m] = Vst[k * KSTR + d];
    }
    #pragma unroll
    for (int uu = 0; uu < 4; ++uu) {
        const int cc = (kh >> 3) + uu;
        *(uint4*)&Vout[(cc * 128 + d) * 8] = *(const uint4*)&tmp[uu * 8];
    }
    __syncthreads();
    unsigned short* outV = Vtb + ((size_t)bh * 32 + t) * TILE;
    #pragma unroll
    for (int u = 0; u < 4; ++u) {
        const int s = u * 256 + tid;
        *(uint4*)(outV + s * 8) = *(const uint4*)&Vout[s * 8];
    }
}

__global__ __launch_bounds__(1024, 1) void fa_fwd(
    const float* __restrict__ Q,
    const unsigned short* __restrict__ Kb,
    const unsigned short* __restrict__ Vtb,
    const int* __restrict__ causal_p,
    float* __restrict__ Op)
{
    __shared__ float mbf[3][4][64 * MST];   // 3 writer regions x 4 q-groups (~99 KB)
    __shared__ float lbf[3][4][32];

    const int tid  = threadIdx.x;
    const int w    = tid >> 6;   // wave 0..15
    const int lane = tid & 63;
    const int ln   = lane & 31;
    const int half = lane >> 5;
    const int qw   = w & 3;          // q-group (32 rows)
    const int nt   = (w >> 2) & 1;   // k-half of the 64-row KV tile
    const int jt   = w >> 3;         // tile parity (even/odd tiles of the phase)
    const int pi   = w >> 2;         // partial index 0..3 (nt + 2*jt)

    // XCD-pinned remap (4 bh per XCD -> K/V workspace L2-resident).
    int bh, qp;
    if (gridDim.x == 8 && gridDim.y == 32) {
        const int lid = blockIdx.x + (blockIdx.y << 3);
        const int xcd = lid & 7;
        const int ii  = lid >> 3;             // 0..31
        bh = (xcd << 2) + (ii & 3);
        qp = ii >> 2;                         // 0..7
    } else {
        bh = blockIdx.y;
        qp = blockIdx.x;
    }
    const int b = bh >> 4;
    const int h = bh & 15;
    const int causal = *causal_p;
    const float cfold = 0.12751743f;  // (1/sqrt(D)) * log2(e), folded into Q

    const unsigned short* Kc = Kb  + (size_t)bh * (32 * TILE);
    const unsigned short* Vc = Vtb + (size_t)bh * (32 * TILE);
    // per-lane invariant offsets (shorts)
    const int koff  = half * 512 + nt * 256 + ln * 8;   // + c*1024 per fragment
    const int vkoff = (nt * 4 + half) * 1024 + ln * 8;  // + win2*2048 + dt*256

    #pragma unroll 1
    for (int ph = 0; ph < 2; ++ph) {
        const int qblk  = ph ? (15 - qp) : qp;   // pair sums to 34 tiles
        const int q0    = qblk * BM;
        const int qrow0 = q0 + qw * 32;
        // phase tile count T = 2*qblk+2 (causal) or 32 (full): ALWAYS even.
        const int T     = causal ? (2 * qblk + 2) : (S / 64);
        const int I     = T >> 1;                // iterations; wave does jj=2i+jt

        // ---- Q fragments (B-operand; lane = q col), pre-scaled ----
        bf16x8 qf[8];
        {
            const size_t rowoff = ((size_t)(b * S + qrow0 + ln) * H + h) * D;
            #pragma unroll
            for (int c = 0; c < 8; ++c) {
                float4 f0 = *(const float4*)(Q + rowoff + c * 16 + half * 8);
                float4 f1 = *(const float4*)(Q + rowoff + c * 16 + half * 8 + 4);
                unsigned int t[4];
                t[0] = pk2(f0.x * cfold, f0.y * cfold);
                t[1] = pk2(f0.z * cfold, f0.w * cfold);
                t[2] = pk2(f1.x * cfold, f1.y * cfold);
                t[3] = pk2(f1.z * cfold, f1.w * cfold);
                qf[c] = *(const bf16x8*)t;
            }
        }

        f32x16 o[4];
        #pragma unroll
        for (int dt = 0; dt < 4; ++dt)
            #pragma unroll
            for (int r = 0; r < 16; ++r) o[dt][r] = 0.0f;
        float l0 = 0.0f, l1 = 0.0f;

        // activity is monotone: act(jj) false => act(jj+2) false
        // ---- register prefetch of tile jt (wave-private; no barriers) ----
        uint4 kr[8], vr[8];
        if ((!causal) || (jt * 64 + nt * 32 <= qrow0 + 31)) {
            const unsigned short* kt = Kc + (size_t)jt * TILE;
            const unsigned short* vt = Vc + (size_t)jt * TILE;
            #pragma unroll
            for (int c = 0; c < 8; ++c)
                kr[c] = *(const uint4*)(kt + c * 1024 + koff);
            #pragma unroll
            for (int i = 0; i < 8; ++i)
                vr[i] = *(const uint4*)(vt + (i >> 2) * 2048 + (i & 3) * 256 + vkoff);
        }

        #pragma unroll 1
        for (int i = 0; i < I; ++i) {
            const int jj = 2 * i + jt;
            const bool aj = (!causal) || (jj * 64 + nt * 32 <= qrow0 + 31);
            const bool an = (i + 1 < I) &&
                            ((!causal) || ((jj + 2) * 64 + nt * 32 <= qrow0 + 31));

            // ---- S^T = K Q^T from registers ----
            f32x16 sacc;
            if (aj) {
                #pragma unroll
                for (int r = 0; r < 16; ++r) sacc[r] = 0.0f;
                __builtin_amdgcn_s_setprio(1);
                #pragma unroll
                for (int c = 0; c < 8; ++c) {
                    bf16x8 kf = *(const bf16x8*)&kr[c];
                    sacc = __builtin_amdgcn_mfma_f32_32x32x16_bf16(kf, qf[c], sacc, 0, 0, 0);
                }
                __builtin_amdgcn_s_setprio(0);
            }
            // ---- prefetch K(jj+2) (kr consumed above; WAR-safe in-order) ----
            if (an) {
                const unsigned short* kt = Kc + (size_t)(jj + 2) * TILE;
                #pragma unroll
                for (int c = 0; c < 8; ++c)
                    kr[c] = *(const uint4*)(kt + c * 1024 + koff);
            }

            if (aj) {
                // ---- fused softmax numerator + PV (P never materializes) ----
                const int thr  = qrow0 + ln - jj * 64;
                const bool full = (!causal) || (jj * 64 + 63 <= qrow0);
                __builtin_amdgcn_s_setprio(1);
                #pragma unroll
                for (int win2 = 0; win2 < 2; ++win2) {
                    unsigned int pw[4];
                    #pragma unroll
                    for (int d2 = 0; d2 < 4; ++d2) {
                        const int r0 = win2 * 8 + 2 * d2;
                        const int r1 = r0 + 1;
                        float e0 = __builtin_amdgcn_exp2f(sacc[r0]);
                        float e1 = __builtin_amdgcn_exp2f(sacc[r1]);
                        if (!full) {
                            const int k0 = nt * 32 + (r0 & 3) + 8 * (r0 >> 2) + 4 * half;
                            const int k1 = nt * 32 + (r1 & 3) + 8 * (r1 >> 2) + 4 * half;
                            if (k0 > thr) e0 = 0.0f;
                            if (k1 > thr) e1 = 0.0f;
                        }
                        l0 += e0; l1 += e1;
                        pw[d2] = pk2(e0, e1);
                    }
                    bf16x8 pf = *(const bf16x8*)pw;
                    #pragma unroll
                    for (int dt = 0; dt < 4; ++dt) {
                        bf16x8 vf = *(const bf16x8*)&vr[win2 * 4 + dt];
                        o[dt] = __builtin_amdgcn_mfma_f32_32x32x16_bf16(vf, pf, o[dt], 0, 0, 0);
                    }
                }
                __builtin_amdgcn_s_setprio(0);
            }
            // ---- prefetch V(jj+2) (vr consumed by PV above) ----
            if (an) {
                const unsigned short* vt = Vc + (size_t)(jj + 2) * TILE;
                #pragma unroll
                for (int i2 = 0; i2 < 8; ++i2)
                    vr[i2] = *(const uint4*)(vt + (i2 >> 2) * 2048 + (i2 & 3) * 256 + vkoff);
            }
        }

        // ---- merge 4 partials (nt x jt) per q-group: 3 writers + pi=0 adds ----
        const float l = l0 + l1;
        const float lp = l + __shfl_xor(l, 32);
        float ltot = 1.0f;
        if (pi > 0) {
            float* mb = &mbf[pi - 1][qw][0];
            #pragma unroll
            for (int dt = 0; dt < 2; ++dt)
                #pragma unroll
                for (int r = 0; r < 16; ++r)
                    mb[lane * MST + dt * 16 + r] = o[dt][r];
            if (half == 0) lbf[pi - 1][qw][ln] = lp;
        }
        __syncthreads();
        if (pi == 0) {
            ltot = lp;
            #pragma unroll
            for (int s = 0; s < 3; ++s) {
                const float* mb = &mbf[s][qw][0];
                #pragma unroll
                for (int dt = 0; dt < 2; ++dt)
                    #pragma unroll
                    for (int r = 0; r < 16; ++r)
                        o[dt][r] += mb[lane * MST + dt * 16 + r];
                ltot += lbf[s][qw][ln];
            }
        }
        __syncthreads();
        if (pi > 0) {
            float* mb = &mbf[pi - 1][qw][0];
            #pragma unroll
            for (int dt = 2; dt < 4; ++dt)
                #pragma unroll
                for (int r = 0; r < 16; ++r)
                    mb[lane * MST + (dt - 2) * 16 + r] = o[dt][r];
        }
        __syncthreads();
        if (pi == 0) {
            #pragma unroll
            for (int s = 0; s < 3; ++s) {
                const float* mb = &mbf[s][qw][0];
                #pragma unroll
                for (int dt = 2; dt < 4; ++dt)
                    #pragma unroll
                    for (int r = 0; r < 16; ++r)
                        o[dt][r] += mb[lane * MST + (dt - 2) * 16 + r];
            }

            // ---- epilogue: direct register->global store (lane = q row) ----
            const float inv = 1.0f / ltot;
            float* op = Op + ((size_t)(b * S + qrow0 + ln) * H + h) * D;
            #pragma unroll
            for (int dt = 0; dt < 4; ++dt)
                #pragma unroll
                for (int rq = 0; rq < 4; ++rq) {
                    float4 st;
                    st.x = o[dt][rq * 4 + 0] * inv;
                    st.y = o[dt][rq * 4 + 1] * inv;
                    st.z = o[dt][rq * 4 + 2] * inv;
                    st.w = o[dt][rq * 4 + 3] * inv;
                    *(float4*)(op + dt * 32 + 8 * rq + 4 * half) = st;
                }
        }
        __syncthreads();   // merge scratch reuse across phases
    }
}

extern "C" void kernel_launch(void* const* d_in, const int* in_sizes, int n_in,
                              void* d_out, int out_size, void* d_ws, size_t ws_size,
                              hipStream_t stream) {
    const int B = in_sizes[0] / (S * H * D);   // expect 2
    unsigned short* Kb  = (unsigned short*)d_ws;
    unsigned short* Vtb = Kb + (size_t)B * S * H * D;

    cvt_kv<<<dim3(S / 64, B * H), 256, 0, stream>>>(
        (const float*)d_in[1], (const float*)d_in[2], Kb, Vtb);
    fa_fwd<<<dim3(8, B * H), 1024, 0, stream>>>(
        (const float*)d_in[0], Kb, Vtb, (const int*)d_in[3], (float*)d_out);
}

// Round 8
// 713.801 us; speedup vs baseline: 1.0345x; 1.0345x over previous
//
#include <hip/hip_runtime.h>

typedef short bf16x8 __attribute__((ext_vector_type(8)));
typedef float f32x16 __attribute__((ext_vector_type(16)));

constexpr int S = 2048;
constexpr int H = 16;
constexpr int D = 128;
constexpr int BM = 128;    // q rows per phase (4 q-groups x 32)
constexpr int TILE = 8192; // shorts per 64-row K/V tile (16 KB)
constexpr int KSTR = 136;  // prepass staging LDS stride (shorts)
constexpr int MST  = 33;   // merge scratch stride (floats)

// ---------------------------------------------------------------------------
// Workspace layouts (per (b,h), 32 tiles of 16KB), both REGISTER-direct:
//  K tile (chunk-major): [chunk 0..15][row 0..63] x 16B.  Fragment c of wave
//     (qw,nt): lane(ln,half) reads chunk 2c+half, row nt*32+ln -> coalesced
//     global_load_dwordx4 (consecutive lanes = consecutive 16B).
//  V tile (cc-major, sigma column order): [cc 0..7][d 0..127] x 16B; chunk cc
//     holds k-pairs in the order matching pk2-packed P (sigma interleave).
//
// fa_fwd v8 = v7 with the REGISTER CAP FIXED: __launch_bounds__(1024, 4).
// v7's (1024,1) let the allocator assume 8-waves-per-SIMD packing -> 64 VGPR
// cap -> full spill of the 128-VGPR per-wave state (WRITE_SIZE 1.22 GB, 8x
// slowdown).  (1024,4) pins 512/4 = 128 VGPR, which R6 proved sufficient for
// this exact per-wave body (zero spill at 128).  16 waves/block, 256 blocks,
// 1 block/CU, 4 waves/SIMD; wave (qw,nt,jt) as v7; NO j-loop barriers.
// ---------------------------------------------------------------------------

__device__ inline unsigned int pk2(float a, float b) {
    // pack 2 f32 -> 2 bf16 (RNE bit-trick; finite values only). low=a, high=b
    unsigned int ua = __builtin_bit_cast(unsigned int, a);
    unsigned int ub = __builtin_bit_cast(unsigned int, b);
    ua += 0x7fffu + ((ua >> 16) & 1u);
    ub += 0x7fffu + ((ub >> 16) & 1u);
    return (ua >> 16) | (ub & 0xffff0000u);
}

// ---- fused prepass: K -> chunk-major bf16 tiles; V -> transposed cc-major ----
__global__ __launch_bounds__(256) void cvt_kv(const float* __restrict__ K,
                                              const float* __restrict__ V,
                                              unsigned short* __restrict__ Kb,
                                              unsigned short* __restrict__ Vtb) {
    __shared__ unsigned short Kst[64 * KSTR];
    __shared__ unsigned short Vst[64 * KSTR];
    __shared__ unsigned short Vout[TILE];
    const int tid = threadIdx.x;
    const int t   = blockIdx.x;   // 64-row tile
    const int bh  = blockIdx.y;
    const int b = bh >> 4, h = bh & 15;
    const size_t base = ((size_t)(b * S + t * 64) * H + h) * D;

    // --- stage K and V rows into LDS (coalesced reads, cvt to bf16) ---
    #pragma unroll
    for (int u = 0; u < 4; ++u) {
        const int c   = tid + 256 * u;
        const int n   = c >> 4;
        const int off = (c & 15) * 8;
        const float* pk = K + base + (size_t)n * (H * D) + off;
        float4 f0 = *(const float4*)pk;
        float4 f1 = *(const float4*)(pk + 4);
        unsigned int w[4];
        w[0] = pk2(f0.x, f0.y); w[1] = pk2(f0.z, f0.w);
        w[2] = pk2(f1.x, f1.y); w[3] = pk2(f1.z, f1.w);
        *(uint4*)&Kst[n * KSTR + off] = *(const uint4*)w;
        const float* pv = V + base + (size_t)n * (H * D) + off;
        f0 = *(const float4*)pv;
        f1 = *(const float4*)(pv + 4);
        w[0] = pk2(f0.x, f0.y); w[1] = pk2(f0.z, f0.w);
        w[2] = pk2(f1.x, f1.y); w[3] = pk2(f1.z, f1.w);
        *(uint4*)&Vst[n * KSTR + off] = *(const uint4*)w;
    }
    __syncthreads();

    // --- K: chunk-major linear write ---
    unsigned short* outK = Kb + ((size_t)bh * 32 + t) * TILE;
    #pragma unroll
    for (int u = 0; u < 4; ++u) {
        const int s = u * 256 + tid;        // 16B slot = chunk*64 + row
        const int chunk = s >> 6;
        const int row   = s & 63;
        *(uint4*)(outK + s * 8) = *(const uint4*)&Kst[row * KSTR + chunk * 8];
    }

    // --- V: transpose (sigma pair-interleave) into cc-major Vout, write linear ---
    const int d  = tid >> 1;
    const int kh = (tid & 1) * 32;
    unsigned short tmp[32];
    #pragma unroll
    for (int m = 0; m < 32; ++m) {
        const int sig = kh + m;
        const int k = (sig & ~12) | ((sig & 4) << 1) | ((sig & 8) >> 1);
        tmp[m] = Vst[k * KSTR + d];
    }
    #pragma unroll
    for (int uu = 0; uu < 4; ++uu) {
        const int cc = (kh >> 3) + uu;
        *(uint4*)&Vout[(cc * 128 + d) * 8] = *(const uint4*)&tmp[uu * 8];
    }
    __syncthreads();
    unsigned short* outV = Vtb + ((size_t)bh * 32 + t) * TILE;
    #pragma unroll
    for (int u = 0; u < 4; ++u) {
        const int s = u * 256 + tid;
        *(uint4*)(outV + s * 8) = *(const uint4*)&Vout[s * 8];
    }
}

__global__ __launch_bounds__(1024, 4) void fa_fwd(
    const float* __restrict__ Q,
    const unsigned short* __restrict__ Kb,
    const unsigned short* __restrict__ Vtb,
    const int* __restrict__ causal_p,
    float* __restrict__ Op)
{
    __shared__ float mbf[3][4][64 * MST];   // 3 writer regions x 4 q-groups (~99 KB)
    __shared__ float lbf[3][4][32];

    const int tid  = threadIdx.x;
    const int w    = tid >> 6;   // wave 0..15
    const int lane = tid & 63;
    const int ln   = lane & 31;
    const int half = lane >> 5;
    const int qw   = w & 3;          // q-group (32 rows)
    const int nt   = (w >> 2) & 1;   // k-half of the 64-row KV tile
    const int jt   = w >> 3;         // tile parity (even/odd tiles of the phase)
    const int pi   = w >> 2;         // partial index 0..3 (nt + 2*jt)

    // XCD-pinned remap (4 bh per XCD -> K/V workspace L2-resident).
    int bh, qp;
    if (gridDim.x == 8 && gridDim.y == 32) {
        const int lid = blockIdx.x + (blockIdx.y << 3);
        const int xcd = lid & 7;
        const int ii  = lid >> 3;             // 0..31
        bh = (xcd << 2) + (ii & 3);
        qp = ii >> 2;                         // 0..7
    } else {
        bh = blockIdx.y;
        qp = blockIdx.x;
    }
    const int b = bh >> 4;
    const int h = bh & 15;
    const int causal = *causal_p;
    const float cfold = 0.12751743f;  // (1/sqrt(D)) * log2(e), folded into Q

    const unsigned short* Kc = Kb  + (size_t)bh * (32 * TILE);
    const unsigned short* Vc = Vtb + (size_t)bh * (32 * TILE);
    // per-lane invariant offsets (shorts)
    const int koff  = half * 512 + nt * 256 + ln * 8;   // + c*1024 per fragment
    const int vkoff = (nt * 4 + half) * 1024 + ln * 8;  // + win2*2048 + dt*256

    #pragma unroll 1
    for (int ph = 0; ph < 2; ++ph) {
        const int qblk  = ph ? (15 - qp) : qp;   // pair sums to 34 tiles
        const int q0    = qblk * BM;
        const int qrow0 = q0 + qw * 32;
        // phase tile count T = 2*qblk+2 (causal) or 32 (full): ALWAYS even.
        const int T     = causal ? (2 * qblk + 2) : (S / 64);
        const int I     = T >> 1;                // iterations; wave does jj=2i+jt

        // ---- Q fragments (B-operand; lane = q col), pre-scaled ----
        bf16x8 qf[8];
        {
            const size_t rowoff = ((size_t)(b * S + qrow0 + ln) * H + h) * D;
            #pragma unroll
            for (int c = 0; c < 8; ++c) {
                float4 f0 = *(const float4*)(Q + rowoff + c * 16 + half * 8);
                float4 f1 = *(const float4*)(Q + rowoff + c * 16 + half * 8 + 4);
                unsigned int t[4];
                t[0] = pk2(f0.x * cfold, f0.y * cfold);
                t[1] = pk2(f0.z * cfold, f0.w * cfold);
                t[2] = pk2(f1.x * cfold, f1.y * cfold);
                t[3] = pk2(f1.z * cfold, f1.w * cfold);
                qf[c] = *(const bf16x8*)t;
            }
        }

        f32x16 o[4];
        #pragma unroll
        for (int dt = 0; dt < 4; ++dt)
            #pragma unroll
            for (int r = 0; r < 16; ++r) o[dt][r] = 0.0f;
        float l0 = 0.0f, l1 = 0.0f;

        // activity is monotone: act(jj) false => act(jj+2) false
        // ---- register prefetch of tile jt (wave-private; no barriers) ----
        uint4 kr[8], vr[8];
        if ((!causal) || (jt * 64 + nt * 32 <= qrow0 + 31)) {
            const unsigned short* kt = Kc + (size_t)jt * TILE;
            const unsigned short* vt = Vc + (size_t)jt * TILE;
            #pragma unroll
            for (int c = 0; c < 8; ++c)
                kr[c] = *(const uint4*)(kt + c * 1024 + koff);
            #pragma unroll
            for (int i = 0; i < 8; ++i)
                vr[i] = *(const uint4*)(vt + (i >> 2) * 2048 + (i & 3) * 256 + vkoff);
        }

        #pragma unroll 1
        for (int i = 0; i < I; ++i) {
            const int jj = 2 * i + jt;
            const bool aj = (!causal) || (jj * 64 + nt * 32 <= qrow0 + 31);
            const bool an = (i + 1 < I) &&
                            ((!causal) || ((jj + 2) * 64 + nt * 32 <= qrow0 + 31));

            // ---- S^T = K Q^T from registers ----
            f32x16 sacc;
            if (aj) {
                #pragma unroll
                for (int r = 0; r < 16; ++r) sacc[r] = 0.0f;
                __builtin_amdgcn_s_setprio(1);
                #pragma unroll
                for (int c = 0; c < 8; ++c) {
                    bf16x8 kf = *(const bf16x8*)&kr[c];
                    sacc = __builtin_amdgcn_mfma_f32_32x32x16_bf16(kf, qf[c], sacc, 0, 0, 0);
                }
                __builtin_amdgcn_s_setprio(0);
            }
            // ---- prefetch K(jj+2) (kr consumed above; WAR-safe in-order) ----
            if (an) {
                const unsigned short* kt = Kc + (size_t)(jj + 2) * TILE;
                #pragma unroll
                for (int c = 0; c < 8; ++c)
                    kr[c] = *(const uint4*)(kt + c * 1024 + koff);
            }

            if (aj) {
                // ---- fused softmax numerator + PV (P never materializes) ----
                const int thr  = qrow0 + ln - jj * 64;
                const bool full = (!causal) || (jj * 64 + 63 <= qrow0);
                __builtin_amdgcn_s_setprio(1);
                #pragma unroll
                for (int win2 = 0; win2 < 2; ++win2) {
                    unsigned int pw[4];
                    #pragma unroll
                    for (int d2 = 0; d2 < 4; ++d2) {
                        const int r0 = win2 * 8 + 2 * d2;
                        const int r1 = r0 + 1;
                        float e0 = __builtin_amdgcn_exp2f(sacc[r0]);
                        float e1 = __builtin_amdgcn_exp2f(sacc[r1]);
                        if (!full) {
                            const int k0 = nt * 32 + (r0 & 3) + 8 * (r0 >> 2) + 4 * half;
                            const int k1 = nt * 32 + (r1 & 3) + 8 * (r1 >> 2) + 4 * half;
                            if (k0 > thr) e0 = 0.0f;
                            if (k1 > thr) e1 = 0.0f;
                        }
                        l0 += e0; l1 += e1;
                        pw[d2] = pk2(e0, e1);
                    }
                    bf16x8 pf = *(const bf16x8*)pw;
                    #pragma unroll
                    for (int dt = 0; dt < 4; ++dt) {
                        bf16x8 vf = *(const bf16x8*)&vr[win2 * 4 + dt];
                        o[dt] = __builtin_amdgcn_mfma_f32_32x32x16_bf16(vf, pf, o[dt], 0, 0, 0);
                    }
                }
                __builtin_amdgcn_s_setprio(0);
            }
            // ---- prefetch V(jj+2) (vr consumed by PV above) ----
            if (an) {
                const unsigned short* vt = Vc + (size_t)(jj + 2) * TILE;
                #pragma unroll
                for (int i2 = 0; i2 < 8; ++i2)
                    vr[i2] = *(const uint4*)(vt + (i2 >> 2) * 2048 + (i2 & 3) * 256 + vkoff);
            }
        }

        // ---- merge 4 partials (nt x jt) per q-group: 3 writers + pi=0 adds ----
        const float l = l0 + l1;
        const float lp = l + __shfl_xor(l, 32);
        float ltot = 1.0f;
        if (pi > 0) {
            float* mb = &mbf[pi - 1][qw][0];
            #pragma unroll
            for (int dt = 0; dt < 2; ++dt)
                #pragma unroll
                for (int r = 0; r < 16; ++r)
                    mb[lane * MST + dt * 16 + r] = o[dt][r];
            if (half == 0) lbf[pi - 1][qw][ln] = lp;
        }
        __syncthreads();
        if (pi == 0) {
            ltot = lp;
            #pragma unroll
            for (int s = 0; s < 3; ++s) {
                const float* mb = &mbf[s][qw][0];
                #pragma unroll
                for (int dt = 0; dt < 2; ++dt)
                    #pragma unroll
                    for (int r = 0; r < 16; ++r)
                        o[dt][r] += mb[lane * MST + dt * 16 + r];
                ltot += lbf[s][qw][ln];
            }
        }
        __syncthreads();
        if (pi > 0) {
            float* mb = &mbf[pi - 1][qw][0];
            #pragma unroll
            for (int dt = 2; dt < 4; ++dt)
                #pragma unroll
                for (int r = 0; r < 16; ++r)
                    mb[lane * MST + (dt - 2) * 16 + r] = o[dt][r];
        }
        __syncthreads();
        if (pi == 0) {
            #pragma unroll
            for (int s = 0; s < 3; ++s) {
                const float* mb = &mbf[s][qw][0];
                #pragma unroll
                for (int dt = 2; dt < 4; ++dt)
                    #pragma unroll
                    for (int r = 0; r < 16; ++r)
                        o[dt][r] += mb[lane * MST + (dt - 2) * 16 + r];
            }

            // ---- epilogue: direct register->global store (lane = q row) ----
            const float inv = 1.0f / ltot;
            float* op = Op + ((size_t)(b * S + qrow0 + ln) * H + h) * D;
            #pragma unroll
            for (int dt = 0; dt < 4; ++dt)
                #pragma unroll
                for (int rq = 0; rq < 4; ++rq) {
                    float4 st;
                    st.x = o[dt][rq * 4 + 0] * inv;
                    st.y = o[dt][rq * 4 + 1] * inv;
                    st.z = o[dt][rq * 4 + 2] * inv;
                    st.w = o[dt][rq * 4 + 3] * inv;
                    *(float4*)(op + dt * 32 + 8 * rq + 4 * half) = st;
                }
        }
        __syncthreads();   // merge scratch reuse across phases
    }
}

extern "C" void kernel_launch(void* const* d_in, const int* in_sizes, int n_in,
                              void* d_out, int out_size, void* d_ws, size_t ws_size,
                              hipStream_t stream) {
    const int B = in_sizes[0] / (S * H * D);   // expect 2
    unsigned short* Kb  = (unsigned short*)d_ws;
    unsigned short* Vtb = Kb + (size_t)B * S * H * D;

    cvt_kv<<<dim3(S / 64, B * H), 256, 0, stream>>>(
        (const float*)d_in[1], (const float*)d_in[2], Kb, Vtb);
    fa_fwd<<<dim3(8, B * H), 1024, 0, stream>>>(
        (const float*)d_in[0], Kb, Vtb, (const int*)d_in[3], (float*)d_out);
}

// Round 9
// 276.082 us; speedup vs baseline: 2.6747x; 2.5855x over previous
//
#include <hip/hip_runtime.h>

typedef short bf16x8 __attribute__((ext_vector_type(8)));
typedef float f32x16 __attribute__((ext_vector_type(16)));

constexpr int S = 2048;
constexpr int H = 16;
constexpr int D = 128;
constexpr int BM = 128;    // q rows per phase (4 q-groups x 32)
constexpr int TILE = 8192; // shorts per 64-row K/V tile (16 KB)
constexpr int KSTR = 136;  // prepass staging LDS stride (shorts)
constexpr int MST  = 33;   // merge scratch stride (floats)

// ---------------------------------------------------------------------------
// Workspace layouts (per (b,h), 32 tiles of 16KB), both REGISTER-direct:
//  K tile (chunk-major): [chunk 0..15][row 0..63] x 16B.
//  V tile (cc-major, sigma column order): [cc 0..7][d 0..127] x 16B.
//
// fa_fwd v9 (dh-split, 4 waves/SIMD): 512 blocks x 512 thr, 2 blocks/CU.
// Twin blocks dh=0/1 compute the same (bh, q-pair) but each owns HALF of D
// for PV: o[4]->o[2] (-32 regs).  QK^T + softmax duplicated across twins
// (absorbed by idle SIMD cycles — R6 measured ~3K idle cyc/SIMD/tile);
// l is identical on both twins so no cross-block traffic.  Operand loads are
// JIT (no persistent kr/vr: -64 regs).  Register cap via
// amdgpu_waves_per_eu(4) => <=128 total regs/wave => 4 waves/SIMD co-resident.
// (launch_bounds second-arg semantics proved unreliable in R7/R8: 1024-thr
// blocks pinned 64 VGPR regardless -> full spill.  512-thr is the sane path.)
// All 512 blocks = exactly 34 tiles -> balanced 2/CU; 64 blocks/XCD keeps
// the bh->XCD L2 pinning.
// ---------------------------------------------------------------------------

__device__ inline unsigned int pk2(float a, float b) {
    // pack 2 f32 -> 2 bf16 (RNE bit-trick; finite values only). low=a, high=b
    unsigned int ua = __builtin_bit_cast(unsigned int, a);
    unsigned int ub = __builtin_bit_cast(unsigned int, b);
    ua += 0x7fffu + ((ua >> 16) & 1u);
    ub += 0x7fffu + ((ub >> 16) & 1u);
    return (ua >> 16) | (ub & 0xffff0000u);
}

// ---- fused prepass: K -> chunk-major bf16 tiles; V -> transposed cc-major ----
__global__ __launch_bounds__(256) void cvt_kv(const float* __restrict__ K,
                                              const float* __restrict__ V,
                                              unsigned short* __restrict__ Kb,
                                              unsigned short* __restrict__ Vtb) {
    __shared__ unsigned short Kst[64 * KSTR];
    __shared__ unsigned short Vst[64 * KSTR];
    __shared__ unsigned short Vout[TILE];
    const int tid = threadIdx.x;
    const int t   = blockIdx.x;   // 64-row tile
    const int bh  = blockIdx.y;
    const int b = bh >> 4, h = bh & 15;
    const size_t base = ((size_t)(b * S + t * 64) * H + h) * D;

    // --- stage K and V rows into LDS (coalesced reads, cvt to bf16) ---
    #pragma unroll
    for (int u = 0; u < 4; ++u) {
        const int c   = tid + 256 * u;
        const int n   = c >> 4;
        const int off = (c & 15) * 8;
        const float* pk = K + base + (size_t)n * (H * D) + off;
        float4 f0 = *(const float4*)pk;
        float4 f1 = *(const float4*)(pk + 4);
        unsigned int w[4];
        w[0] = pk2(f0.x, f0.y); w[1] = pk2(f0.z, f0.w);
        w[2] = pk2(f1.x, f1.y); w[3] = pk2(f1.z, f1.w);
        *(uint4*)&Kst[n * KSTR + off] = *(const uint4*)w;
        const float* pv = V + base + (size_t)n * (H * D) + off;
        f0 = *(const float4*)pv;
        f1 = *(const float4*)(pv + 4);
        w[0] = pk2(f0.x, f0.y); w[1] = pk2(f0.z, f0.w);
        w[2] = pk2(f1.x, f1.y); w[3] = pk2(f1.z, f1.w);
        *(uint4*)&Vst[n * KSTR + off] = *(const uint4*)w;
    }
    __syncthreads();

    // --- K: chunk-major linear write ---
    unsigned short* outK = Kb + ((size_t)bh * 32 + t) * TILE;
    #pragma unroll
    for (int u = 0; u < 4; ++u) {
        const int s = u * 256 + tid;        // 16B slot = chunk*64 + row
        const int chunk = s >> 6;
        const int row   = s & 63;
        *(uint4*)(outK + s * 8) = *(const uint4*)&Kst[row * KSTR + chunk * 8];
    }

    // --- V: transpose (sigma pair-interleave) into cc-major Vout, write linear ---
    const int d  = tid >> 1;
    const int kh = (tid & 1) * 32;
    unsigned short tmp[32];
    #pragma unroll
    for (int m = 0; m < 32; ++m) {
        const int sig = kh + m;
        const int k = (sig & ~12) | ((sig & 4) << 1) | ((sig & 8) >> 1);
        tmp[m] = Vst[k * KSTR + d];
    }
    #pragma unroll
    for (int uu = 0; uu < 4; ++uu) {
        const int cc = (kh >> 3) + uu;
        *(uint4*)&Vout[(cc * 128 + d) * 8] = *(const uint4*)&tmp[uu * 8];
    }
    __syncthreads();
    unsigned short* outV = Vtb + ((size_t)bh * 32 + t) * TILE;
    #pragma unroll
    for (int u = 0; u < 4; ++u) {
        const int s = u * 256 + tid;
        *(uint4*)(outV + s * 8) = *(const uint4*)&Vout[s * 8];
    }
}

__global__ __launch_bounds__(512)
__attribute__((amdgpu_waves_per_eu(4)))
void fa_fwd(
    const float* __restrict__ Q,
    const unsigned short* __restrict__ Kb,
    const unsigned short* __restrict__ Vtb,
    const int* __restrict__ causal_p,
    float* __restrict__ Op)
{
    __shared__ float mbf[4][64 * MST];   // merge scratch (~34 KB; 2 blocks/CU ok)
    __shared__ float lbf[4][32];

    const int tid  = threadIdx.x;
    const int w    = tid >> 6;   // wave 0..7
    const int lane = tid & 63;
    const int ln   = lane & 31;
    const int half = lane >> 5;
    const int qw   = w & 3;      // q-group (32 rows)
    const int nt   = w >> 2;     // k-half of the 64-row KV tile

    // XCD-pinned remap: 512 blocks, 64/XCD, 4 bh per XCD (K/V L2-resident).
    int bh, qp, dh;
    if (gridDim.x == 16 && gridDim.y == 32) {
        const int lid = blockIdx.x + (blockIdx.y << 4);
        const int xcd = lid & 7;
        const int ii  = lid >> 3;             // 0..63
        bh = (xcd << 2) + (ii & 3);
        const int rest = ii >> 2;             // 0..15
        qp = rest & 7;
        dh = rest >> 3;                       // output D-half owner
    } else {
        bh = blockIdx.y;
        qp = blockIdx.x & 7;
        dh = blockIdx.x >> 3;
    }
    const int b = bh >> 4;
    const int h = bh & 15;
    const int causal = *causal_p;
    const float cfold = 0.12751743f;  // (1/sqrt(D)) * log2(e), folded into Q

    const unsigned short* Kc = Kb  + (size_t)bh * (32 * TILE);
    const unsigned short* Vc = Vtb + (size_t)bh * (32 * TILE);
    // per-lane invariant offsets (shorts)
    const int koff  = half * 512 + nt * 256 + ln * 8;   // + c*1024 per fragment
    const int vkoff = (nt * 4 + half) * 1024 + ln * 8;  // + win2*2048 + dt*256

    #pragma unroll 1
    for (int ph = 0; ph < 2; ++ph) {
        const int qblk  = ph ? (15 - qp) : qp;   // pair sums to 34 tiles
        const int q0    = qblk * BM;
        const int qrow0 = q0 + qw * 32;
        const int jmax  = causal ? ((q0 + BM - 1) >> 6) : (S / 64 - 1);

        // ---- Q fragments (B-operand; lane = q col), pre-scaled ----
        bf16x8 qf[8];
        {
            const size_t rowoff = ((size_t)(b * S + qrow0 + ln) * H + h) * D;
            #pragma unroll
            for (int c = 0; c < 8; ++c) {
                float4 f0 = *(const float4*)(Q + rowoff + c * 16 + half * 8);
                float4 f1 = *(const float4*)(Q + rowoff + c * 16 + half * 8 + 4);
                unsigned int t[4];
                t[0] = pk2(f0.x * cfold, f0.y * cfold);
                t[1] = pk2(f0.z * cfold, f0.w * cfold);
                t[2] = pk2(f1.x * cfold, f1.y * cfold);
                t[3] = pk2(f1.z * cfold, f1.w * cfold);
                qf[c] = *(const bf16x8*)t;
            }
        }

        f32x16 o[2];   // this block's D-half (dt = dh*2 + {0,1})
        #pragma unroll
        for (int dt2 = 0; dt2 < 2; ++dt2)
            #pragma unroll
            for (int r = 0; r < 16; ++r) o[dt2][r] = 0.0f;
        float l0 = 0.0f, l1 = 0.0f;

        #pragma unroll 1
        for (int j = 0; j <= jmax; ++j) {
            const bool aj = (!causal) || (j * 64 + nt * 32 <= qrow0 + 31);
            if (!aj) continue;   // monotone: stays false

            const unsigned short* kt = Kc + (size_t)j * TILE;
            const unsigned short* vt = Vc + (size_t)j * TILE;

            // ---- JIT K fragment loads (cluster; 4-wave TLP hides L2) ----
            uint4 kr[8];
            #pragma unroll
            for (int c = 0; c < 8; ++c)
                kr[c] = *(const uint4*)(kt + c * 1024 + koff);
            // ---- JIT V fragment loads for this D-half ----
            uint4 vr[4];
            #pragma unroll
            for (int i = 0; i < 4; ++i)
                vr[i] = *(const uint4*)(vt + vkoff + (i >> 1) * 2048 +
                                        (dh * 2 + (i & 1)) * 256);

            // ---- S^T = K Q^T (duplicated across dh twins) ----
            f32x16 sacc;
            #pragma unroll
            for (int r = 0; r < 16; ++r) sacc[r] = 0.0f;
            __builtin_amdgcn_s_setprio(1);
            #pragma unroll
            for (int c = 0; c < 8; ++c) {
                bf16x8 kf = *(const bf16x8*)&kr[c];
                sacc = __builtin_amdgcn_mfma_f32_32x32x16_bf16(kf, qf[c], sacc, 0, 0, 0);
            }
            __builtin_amdgcn_s_setprio(0);

            // ---- fused softmax numerator + PV (P never materializes) ----
            const int thr  = qrow0 + ln - j * 64;
            const bool full = (!causal) || (j * 64 + 63 <= qrow0);
            __builtin_amdgcn_s_setprio(1);
            #pragma unroll
            for (int win2 = 0; win2 < 2; ++win2) {
                unsigned int pw[4];
                #pragma unroll
                for (int d2 = 0; d2 < 4; ++d2) {
                    const int r0 = win2 * 8 + 2 * d2;
                    const int r1 = r0 + 1;
                    float e0 = __builtin_amdgcn_exp2f(sacc[r0]);
                    float e1 = __builtin_amdgcn_exp2f(sacc[r1]);
                    if (!full) {
                        const int k0 = nt * 32 + (r0 & 3) + 8 * (r0 >> 2) + 4 * half;
                        const int k1 = nt * 32 + (r1 & 3) + 8 * (r1 >> 2) + 4 * half;
                        if (k0 > thr) e0 = 0.0f;
                        if (k1 > thr) e1 = 0.0f;
                    }
                    l0 += e0; l1 += e1;
                    pw[d2] = pk2(e0, e1);
                }
                bf16x8 pf = *(const bf16x8*)pw;
                #pragma unroll
                for (int dt2 = 0; dt2 < 2; ++dt2) {
                    bf16x8 vf = *(const bf16x8*)&vr[win2 * 2 + dt2];
                    o[dt2] = __builtin_amdgcn_mfma_f32_32x32x16_bf16(vf, pf, o[dt2], 0, 0, 0);
                }
            }
            __builtin_amdgcn_s_setprio(0);
        }

        // ---- merge k-halves within block (l identical across dh twins) ----
        const float l = l0 + l1;
        const float lp = l + __shfl_xor(l, 32);
        if (nt == 1) {
            float* mb = mbf[qw];
            #pragma unroll
            for (int dt2 = 0; dt2 < 2; ++dt2)
                #pragma unroll
                for (int r = 0; r < 16; ++r)
                    mb[lane * MST + dt2 * 16 + r] = o[dt2][r];
            if (half == 0) lbf[qw][ln] = lp;
        }
        __syncthreads();
        if (nt == 0) {
            const float* mb = mbf[qw];
            #pragma unroll
            for (int dt2 = 0; dt2 < 2; ++dt2)
                #pragma unroll
                for (int r = 0; r < 16; ++r)
                    o[dt2][r] += mb[lane * MST + dt2 * 16 + r];
            const float ltot = lp + lbf[qw][ln];

            // ---- epilogue: direct register->global store of this D-half ----
            const float inv = 1.0f / ltot;
            float* op = Op + ((size_t)(b * S + qrow0 + ln) * H + h) * D;
            #pragma unroll
            for (int dt2 = 0; dt2 < 2; ++dt2)
                #pragma unroll
                for (int rq = 0; rq < 4; ++rq) {
                    float4 st;
                    st.x = o[dt2][rq * 4 + 0] * inv;
                    st.y = o[dt2][rq * 4 + 1] * inv;
                    st.z = o[dt2][rq * 4 + 2] * inv;
                    st.w = o[dt2][rq * 4 + 3] * inv;
                    *(float4*)(op + (dh * 2 + dt2) * 32 + 8 * rq + 4 * half) = st;
                }
        }
        __syncthreads();   // merge scratch reuse across phases
    }
}

extern "C" void kernel_launch(void* const* d_in, const int* in_sizes, int n_in,
                              void* d_out, int out_size, void* d_ws, size_t ws_size,
                              hipStream_t stream) {
    const int B = in_sizes[0] / (S * H * D);   // expect 2
    unsigned short* Kb  = (unsigned short*)d_ws;
    unsigned short* Vtb = Kb + (size_t)B * S * H * D;

    cvt_kv<<<dim3(S / 64, B * H), 256, 0, stream>>>(
        (const float*)d_in[1], (const float*)d_in[2], Kb, Vtb);
    fa_fwd<<<dim3(16, B * H), 512, 0, stream>>>(
        (const float*)d_in[0], Kb, Vtb, (const int*)d_in[3], (float*)d_out);
}